// Round 2
// baseline (2163.198 us; speedup 1.0000x reference)
//
#include <hip/hip_runtime.h>

#define B_ 64
#define T_ 243
#define J_ 17
#define C_ 128
#define NTOT (B_*T_*J_*C_)   // 33841152

// LDS layout:
//   [0, 124416)       yf  : float [243][128]     (phases A, C)
//   -- after repack --
//   [0, 62208)        ypk : u32   [243][64]      (packed bf16 pairs)
//   [62208, 124416)   yv  : u16   [243][128]     (yV bf16)
//   [124416, 126360)  nbr : u16   [243][4]
#define SMEM_BYTES 126464

__device__ __forceinline__ float bflo(unsigned p){ return __uint_as_float(p << 16); }
__device__ __forceinline__ float bfhi(unsigned p){ return __uint_as_float(p & 0xffff0000u); }
__device__ __forceinline__ float b2f(unsigned short v){ return __uint_as_float(((unsigned)v) << 16); }
__device__ __forceinline__ unsigned short f2bf(float f){
  unsigned u = __float_as_uint(f);
  u += 0x7fffu + ((u >> 16) & 1u);   // round-to-nearest-even
  return (unsigned short)(u >> 16);
}

extern "C" __global__ void __launch_bounds__(256)
graphblock_kernel(const float* __restrict__ x,
                  const float* __restrict__ att,
                  const float* __restrict__ lnw,
                  const float* __restrict__ lnb,
                  const float* __restrict__ Uw,
                  const float* __restrict__ Ubv,
                  const float* __restrict__ Vw,
                  const float* __restrict__ Vbv,
                  const float* __restrict__ bnw,
                  const float* __restrict__ bnb,
                  const float* __restrict__ ls1,
                  float* __restrict__ out)
{
  extern __shared__ char smem[];
  float*          yf  = (float*)smem;
  unsigned*       ypk = (unsigned*)smem;
  unsigned short* yv  = (unsigned short*)(smem + 62208);
  unsigned short* nbr = (unsigned short*)(smem + 124416);

  const int n = blockIdx.x;
  const int b = n / J_, j = n % J_;
  const int tid  = threadIdx.x;
  const int lane = tid & 63;
  const int wv   = tid >> 6;

  // ---------------- Phase A: LayerNorm -> yf (f32) ----------------
  {
    const float lw0 = lnw[2*lane], lw1 = lnw[2*lane+1];
    const float lb0 = lnb[2*lane], lb1 = lnb[2*lane+1];
    for (int r = wv; r < T_; r += 4) {
      const float2* xr = (const float2*)(x + (((size_t)(b*T_ + r)*J_ + j) << 7));
      float2 p = xr[lane];
      float v0 = p.x, v1 = p.y;
      float s = v0 + v1;
      #pragma unroll
      for (int m = 1; m < 64; m <<= 1) s += __shfl_xor(s, m, 64);
      float mu = s * (1.0f/128.0f);
      float d0 = v0 - mu, d1 = v1 - mu;
      float q = d0*d0 + d1*d1;
      #pragma unroll
      for (int m = 1; m < 64; m <<= 1) q += __shfl_xor(q, m, 64);
      float rs = rsqrtf(q * (1.0f/128.0f) + 1e-5f);
      float y0 = d0*rs*lw0 + lb0;
      float y1 = d1*rs*lw1 + lb1;
      yf[r*C_ + 2*lane]     = y0;
      yf[r*C_ + 2*lane + 1] = y1;
    }
  }
  __syncthreads();

  // ---------------- Phase C: sim = y y^T, top-4 per row ----------------
  if (tid < T_) {
    float yr[128];
    const float4* yme = (const float4*)(yf + tid*C_);
    #pragma unroll
    for (int k4 = 0; k4 < 32; k4++) {
      float4 v = yme[k4];
      yr[4*k4+0]=v.x; yr[4*k4+1]=v.y; yr[4*k4+2]=v.z; yr[4*k4+3]=v.w;
    }
    float v0=-3e38f, v1=-3e38f, v2=-3e38f, v3=-3e38f;
    int   i0=0, i1=0, i2=0, i3=0;
    for (int s = 0; s < T_; s++) {
      const float4* ys = (const float4*)(yf + s*C_);
      float a0=0.f, a1=0.f, a2=0.f, a3=0.f;
      #pragma unroll
      for (int k4 = 0; k4 < 32; k4 += 4) {
        float4 w0 = ys[k4+0], w1 = ys[k4+1], w2 = ys[k4+2], w3 = ys[k4+3];
        a0 = fmaf(yr[4*k4+0],  w0.x, a0); a0 = fmaf(yr[4*k4+1],  w0.y, a0);
        a0 = fmaf(yr[4*k4+2],  w0.z, a0); a0 = fmaf(yr[4*k4+3],  w0.w, a0);
        a1 = fmaf(yr[4*k4+4],  w1.x, a1); a1 = fmaf(yr[4*k4+5],  w1.y, a1);
        a1 = fmaf(yr[4*k4+6],  w1.z, a1); a1 = fmaf(yr[4*k4+7],  w1.w, a1);
        a2 = fmaf(yr[4*k4+8],  w2.x, a2); a2 = fmaf(yr[4*k4+9],  w2.y, a2);
        a2 = fmaf(yr[4*k4+10], w2.z, a2); a2 = fmaf(yr[4*k4+11], w2.w, a2);
        a3 = fmaf(yr[4*k4+12], w3.x, a3); a3 = fmaf(yr[4*k4+13], w3.y, a3);
        a3 = fmaf(yr[4*k4+14], w3.z, a3); a3 = fmaf(yr[4*k4+15], w3.w, a3);
      }
      float acc = (a0+a1)+(a2+a3);
      if (acc > v3) {
        if (acc > v0)      { v3=v2;i3=i2; v2=v1;i2=i1; v1=v0;i1=i0; v0=acc;i0=s; }
        else if (acc > v1) { v3=v2;i3=i2; v2=v1;i2=i1; v1=acc;i1=s; }
        else if (acc > v2) { v3=v2;i3=i2; v2=acc;i2=s; }
        else               { v3=acc;i3=s; }
      }
    }
    nbr[tid*4+0]=(unsigned short)i0; nbr[tid*4+1]=(unsigned short)i1;
    nbr[tid*4+2]=(unsigned short)i2; nbr[tid*4+3]=(unsigned short)i3;
  }
  __syncthreads();

  // ---------------- Repack yf (f32) -> ypk (bf16x2) in place ----------------
  {
    unsigned buf[61];
    #pragma unroll
    for (int it = 0; it < 61; it++) {
      int i = tid + it*256;
      if (i < T_*64) {
        float a = yf[2*i], c = yf[2*i+1];
        buf[it] = (unsigned)f2bf(a) | ((unsigned)f2bf(c) << 16);
      }
    }
    __syncthreads();
    #pragma unroll
    for (int it = 0; it < 61; it++) {
      int i = tid + it*256;
      if (i < T_*64) ypk[i] = buf[it];
    }
  }
  __syncthreads();

  // ---------------- Phase B: yV = y @ Vw^T + Vb -> yv (bf16) ----------------
  {
    const int c  = tid & 127;
    const int t0 = tid >> 7;
    float wrow[128];
    const float4* vw4 = (const float4*)(Vw + c*C_);
    #pragma unroll
    for (int k4 = 0; k4 < 32; k4++) {
      float4 w = vw4[k4];
      wrow[4*k4+0]=w.x; wrow[4*k4+1]=w.y; wrow[4*k4+2]=w.z; wrow[4*k4+3]=w.w;
    }
    const float vb = Vbv[c];
    for (int it = 0; it < 122; it++) {
      int t = t0 + it*2;
      if (t < T_) {
        float a0=vb, a1=0.f;
        #pragma unroll
        for (int k2 = 0; k2 < 64; k2 += 2) {
          unsigned p0 = ypk[t*64 + k2], p1 = ypk[t*64 + k2 + 1];
          a0 = fmaf(bflo(p0), wrow[2*k2+0], a0);
          a0 = fmaf(bfhi(p0), wrow[2*k2+1], a0);
          a1 = fmaf(bflo(p1), wrow[2*k2+2], a1);
          a1 = fmaf(bfhi(p1), wrow[2*k2+3], a1);
        }
        yv[t*C_ + c] = f2bf(a0 + a1);
      }
    }
  }
  __syncthreads();

  // ---------------- Phase D: agg + yU + BN + ReLU + epilogue ----------------
  {
    const int c  = tid & 127;
    const int t0 = tid >> 7;
    float urow[128];
    const float4* uw4 = (const float4*)(Uw + c*C_);
    #pragma unroll
    for (int k4 = 0; k4 < 32; k4++) {
      float4 w = uw4[k4];
      urow[4*k4+0]=w.x; urow[4*k4+1]=w.y; urow[4*k4+2]=w.z; urow[4*k4+3]=w.w;
    }
    const float ubc  = Ubv[c];
    const float lsc  = ls1[c];
    const float bnrs = rsqrtf(1.0f + 1e-5f);
    for (int it = 0; it < 122; it++) {
      int t = t0 + it*2;
      if (t < T_) {
        float aggv = 0.f;
        #pragma unroll
        for (int i = 0; i < 4; i++) {
          int s = nbr[t*4 + i];
          aggv += b2f(yv[s*C_ + c]);
        }
        aggv *= 0.25f;   // dinv_t * dinv_s with deg == 4
        float a0=ubc, a1=0.f;
        #pragma unroll
        for (int k2 = 0; k2 < 64; k2 += 2) {
          unsigned p0 = ypk[t*64 + k2], p1 = ypk[t*64 + k2 + 1];
          a0 = fmaf(bflo(p0), urow[2*k2+0], a0);
          a0 = fmaf(bfhi(p0), urow[2*k2+1], a0);
          a1 = fmaf(bflo(p1), urow[2*k2+2], a1);
          a1 = fmaf(bfhi(p1), urow[2*k2+3], a1);
        }
        float h = aggv + (a0 + a1);
        h = h * (bnw[t] * bnrs) + bnb[t];
        unsigned yp = ypk[t*64 + (c>>1)];
        float yc = (c & 1) ? bfhi(yp) : bflo(yp);
        float z  = fmaxf(0.f, yc + h);
        float gx = lsc * z;
        size_t g = ((size_t)(b*T_ + t)*J_ + j)*C_ + c;
        float xf = x[g], af = att[g];
        out[g]        = gx + af + xf;
        out[NTOT + g] = gx * 0.5f;
      }
    }
  }
}

extern "C" void kernel_launch(void* const* d_in, const int* in_sizes, int n_in,
                              void* d_out, int out_size, void* d_ws, size_t ws_size,
                              hipStream_t stream) {
  hipFuncSetAttribute(reinterpret_cast<const void*>(graphblock_kernel),
                      hipFuncAttributeMaxDynamicSharedMemorySize, SMEM_BYTES);
  dim3 grid(B_ * J_);
  dim3 block(256);
  graphblock_kernel<<<grid, block, SMEM_BYTES, stream>>>(
      (const float*)d_in[0],  // x
      (const float*)d_in[1],  // attention_feat
      (const float*)d_in[2],  // ln_w
      (const float*)d_in[3],  // ln_b
      (const float*)d_in[4],  // Uw
      (const float*)d_in[5],  // Ub
      (const float*)d_in[6],  // Vw
      (const float*)d_in[7],  // Vb
      (const float*)d_in[8],  // bn_w
      (const float*)d_in[9],  // bn_b
      (const float*)d_in[10], // ls1
      (float*)d_out);
}

// Round 3
// 475.454 us; speedup vs baseline: 4.5498x; 4.5498x over previous
//
#include <hip/hip_runtime.h>

#define B_ 64
#define T_ 243
#define J_ 17
#define C_ 128
#define JC (J_*C_)            // 2176
#define NTOT (B_*T_*J_*C_)    // 33841152

// LDS layout (bytes):
//   [0,      65536)  ylds : bf16 [256][128], swizzled: byte = r*256 + (kb ^ ((r&7)<<4))
//   [65536, 132096)  simbuf: f32 [64][260] (sim strips)  -- later yv: bf16 rows, stride 264 B
//   [132096,134144)  nbr : u16 [256][4]
//   [134144,135168)  bnw_s : f32 [243] (pre-scaled)
//   [135168,136192)  bnb_s : f32 [243]
#define YOFF    0
#define SIMOFF  65536
#define YVOFF   65536
#define NBROFF  132096
#define BNWOFF  134144
#define BNBOFF  135168
#define SMEM_BYTES 136192

typedef short bf16x8 __attribute__((ext_vector_type(8)));
typedef float f32x4 __attribute__((ext_vector_type(4)));

__device__ __forceinline__ float b2f(unsigned short v){ return __uint_as_float(((unsigned)v) << 16); }
__device__ __forceinline__ unsigned short f2bf(float f){
  unsigned u = __float_as_uint(f);
  u += 0x7fffu + ((u >> 16) & 1u);   // RNE
  return (unsigned short)(u >> 16);
}
__device__ __forceinline__ bf16x8 pack8(float4 a, float4 b){
  union { bf16x8 v; unsigned short u[8]; } r;
  r.u[0]=f2bf(a.x); r.u[1]=f2bf(a.y); r.u[2]=f2bf(a.z); r.u[3]=f2bf(a.w);
  r.u[4]=f2bf(b.x); r.u[5]=f2bf(b.y); r.u[6]=f2bf(b.z); r.u[7]=f2bf(b.w);
  return r.v;
}

// branchless top-4 insert (desc). Uses/updates v0..v3, i0..i3 in scope.
#define INSERT(v, idx) do { \
  bool g0 = (v) > v0, g1 = (v) > v1, g2 = (v) > v2, g3 = (v) > v3; \
  v3 = g2 ? v2 : (g3 ? (v) : v3);  i3 = g2 ? i2 : (g3 ? (idx) : i3); \
  v2 = g1 ? v1 : (g2 ? (v) : v2);  i2 = g1 ? i1 : (g2 ? (idx) : i2); \
  v1 = g0 ? v0 : (g1 ? (v) : v1);  i1 = g0 ? i0 : (g1 ? (idx) : i1); \
  v0 = g0 ? (v) : v0;              i0 = g0 ? (idx) : i0; \
} while(0)

extern "C" __global__ void __launch_bounds__(512)
graphblock_kernel(const float* __restrict__ x, const float* __restrict__ att,
                  const float* __restrict__ lnw, const float* __restrict__ lnb,
                  const float* __restrict__ Uw, const float* __restrict__ Ubv,
                  const float* __restrict__ Vw, const float* __restrict__ Vbv,
                  const float* __restrict__ bnw, const float* __restrict__ bnb,
                  const float* __restrict__ ls1, float* __restrict__ out)
{
  extern __shared__ char smem[];
  const int tid = threadIdx.x;
  const int w   = tid >> 6;     // wave 0..7
  const int l   = tid & 63;     // lane
  const int lr  = l & 15;       // row/col-in-tile for A/B frags
  const int lg  = l >> 4;       // k-group
  const int n = blockIdx.x;
  const int b = n / J_, j = n % J_;
  const long nbase = (long)b*T_*JC + (long)j*C_;

  // stage BN tables
  if (tid < T_) {
    ((float*)(smem+BNWOFF))[tid] = bnw[tid] * rsqrtf(1.0f + 1e-5f);
    ((float*)(smem+BNBOFF))[tid] = bnb[tid];
  }

  // ---------- Phase A: LayerNorm -> ylds (bf16, swizzled), zero-pad rows 243..255 ----------
  {
    const float lw0 = lnw[2*l], lw1 = lnw[2*l+1];
    const float lb0 = lnb[2*l], lb1 = lnb[2*l+1];
    for (int r = w; r < 256; r += 8) {
      unsigned pk = 0u;
      if (r < T_) {
        const float2* xr = (const float2*)(x + nbase + (long)r*JC);
        float2 p = xr[l];
        float s = p.x + p.y;
        #pragma unroll
        for (int m=1;m<64;m<<=1) s += __shfl_xor(s, m, 64);
        float mu = s * (1.0f/128.0f);
        float d0 = p.x - mu, d1 = p.y - mu;
        float q = d0*d0 + d1*d1;
        #pragma unroll
        for (int m=1;m<64;m<<=1) q += __shfl_xor(q, m, 64);
        float rs = rsqrtf(q*(1.0f/128.0f) + 1e-5f);
        pk = (unsigned)f2bf(d0*rs*lw0 + lb0) | ((unsigned)f2bf(d1*rs*lw1 + lb1) << 16);
      }
      *(unsigned*)(smem + YOFF + r*256 + ((4*l) ^ ((r&7)<<4))) = pk;
    }
  }
  __syncthreads();

  // ---------- Phase C: sim strips (MFMA) + top-4 scan ----------
  {
    float* sb = (float*)(smem + SIMOFF);
    const int rg = w & 3, sh = w >> 2;
    for (int ts = 0; ts < 4; ts++) {
      const int t0s = ts*64;
      // MFMA: wave computes 16 t-rows x 128 s-cols
      {
        const int ar = t0s + rg*16 + lr;
        bf16x8 afr[4];
        #pragma unroll
        for (int kk=0;kk<4;kk++)
          afr[kk] = *(const bf16x8*)(smem + YOFF + ar*256 + ((kk*64 + lg*16) ^ ((ar&7)<<4)));
        for (int st=0; st<8; st++) {
          const int s0 = (sh*8 + st)*16;
          const int br = s0 + lr;
          f32x4 acc = {0.f,0.f,0.f,0.f};
          #pragma unroll
          for (int kk=0;kk<4;kk++) {
            bf16x8 bfr = *(const bf16x8*)(smem + YOFF + br*256 + ((kk*64 + lg*16) ^ ((br&7)<<4)));
            acc = __builtin_amdgcn_mfma_f32_16x16x32_bf16(afr[kk], bfr, acc, 0,0,0);
          }
          const int rb = rg*16 + lg*4;
          #pragma unroll
          for (int reg=0;reg<4;reg++)
            sb[(rb+reg)*260 + s0 + lr] = acc[reg];
        }
      }
      __syncthreads();
      // scan: 8 threads per row, butterfly-merge top-4
      {
        const int r = tid >> 3, q = tid & 7;
        const int t = t0s + r;
        float v0=-3e38f,v1=-3e38f,v2=-3e38f,v3=-3e38f;
        int i0=0,i1=0,i2=0,i3=0;
        for (int i=0;i<31;i++){
          int s = q + (i<<3);
          float v = (s < T_) ? sb[r*260 + s] : -3e38f;
          INSERT(v, s);
        }
        #pragma unroll
        for (int m=1;m<8;m<<=1){
          float w0=__shfl_xor(v0,m,64), w1=__shfl_xor(v1,m,64), w2=__shfl_xor(v2,m,64), w3=__shfl_xor(v3,m,64);
          int   j0=__shfl_xor(i0,m,64), j1=__shfl_xor(i1,m,64), j2=__shfl_xor(i2,m,64), j3=__shfl_xor(i3,m,64);
          INSERT(w0,j0); INSERT(w1,j1); INSERT(w2,j2); INSERT(w3,j3);
        }
        if (q==0 && t < T_){
          unsigned long long pk = (unsigned long long)(unsigned short)i0
            | ((unsigned long long)(unsigned short)i1 << 16)
            | ((unsigned long long)(unsigned short)i2 << 32)
            | ((unsigned long long)(unsigned short)i3 << 48);
          *(unsigned long long*)(smem + NBROFF + t*8) = pk;
        }
      }
      __syncthreads();
    }
  }

  // ---------- Phase B: yV = y@Vw^T + Vb (MFMA) -> yv bf16 (stride 264B) ----------
  {
    const int cr = w*16 + lr;
    bf16x8 vfr[4];
    #pragma unroll
    for (int kk=0;kk<4;kk++){
      const float4* p = (const float4*)(Vw + cr*C_ + kk*32 + lg*8);
      vfr[kk] = pack8(p[0], p[1]);
    }
    const float vb = Vbv[cr];
    for (int tt=0; tt<16; tt++){
      const int arow = tt*16 + lr;
      f32x4 acc = {0.f,0.f,0.f,0.f};
      #pragma unroll
      for (int kk=0;kk<4;kk++){
        bf16x8 a = *(const bf16x8*)(smem + YOFF + arow*256 + ((kk*64+lg*16) ^ ((arow&7)<<4)));
        acc = __builtin_amdgcn_mfma_f32_16x16x32_bf16(a, vfr[kk], acc, 0,0,0);
      }
      #pragma unroll
      for (int reg=0;reg<4;reg++){
        int t = tt*16 + lg*4 + reg;
        if (t < T_)
          *(unsigned short*)(smem + YVOFF + t*264 + 2*cr) = f2bf(acc[reg] + vb);
      }
    }
  }
  __syncthreads();

  // ---------- Phase D: yU (MFMA) + gather-agg + BN + ReLU + epilogue ----------
  {
    const int cr = w*16 + lr;
    bf16x8 ufr[4];
    #pragma unroll
    for (int kk=0;kk<4;kk++){
      const float4* p = (const float4*)(Uw + cr*C_ + kk*32 + lg*8);
      ufr[kk] = pack8(p[0], p[1]);
    }
    const float ubc = Ubv[cr];
    const float lsc = ls1[cr];
    for (int tt=0; tt<16; tt++){
      const int arow = tt*16 + lr;
      f32x4 acc = {0.f,0.f,0.f,0.f};
      #pragma unroll
      for (int kk=0;kk<4;kk++){
        bf16x8 a = *(const bf16x8*)(smem + YOFF + arow*256 + ((kk*64+lg*16) ^ ((arow&7)<<4)));
        acc = __builtin_amdgcn_mfma_f32_16x16x32_bf16(a, ufr[kk], acc, 0,0,0);
      }
      #pragma unroll
      for (int reg=0;reg<4;reg++){
        const int t = tt*16 + lg*4 + reg;
        if (t < T_){
          unsigned long long nb = *(const unsigned long long*)(smem + NBROFF + t*8);
          const int s0i = (int)(nb & 0xffffu), s1i = (int)((nb>>16)&0xffffu),
                    s2i = (int)((nb>>32)&0xffffu), s3i = (int)((nb>>48)&0xffffu);
          float agg = b2f(*(const unsigned short*)(smem + YVOFF + s0i*264 + 2*cr))
                    + b2f(*(const unsigned short*)(smem + YVOFF + s1i*264 + 2*cr))
                    + b2f(*(const unsigned short*)(smem + YVOFF + s2i*264 + 2*cr))
                    + b2f(*(const unsigned short*)(smem + YVOFF + s3i*264 + 2*cr));
          float h = 0.25f*agg + acc[reg] + ubc;
          h = h * ((const float*)(smem+BNWOFF))[t] + ((const float*)(smem+BNBOFF))[t];
          float yo = b2f(*(const unsigned short*)(smem + YOFF + t*256 + ((2*cr) ^ ((t&7)<<4))));
          float z = fmaxf(0.f, yo + h);
          float gx = lsc * z;
          long g = nbase + (long)t*JC + cr;
          out[g] = gx + x[g] + att[g];
          out[NTOT + g] = gx * 0.5f;
        }
      }
    }
  }
}

extern "C" void kernel_launch(void* const* d_in, const int* in_sizes, int n_in,
                              void* d_out, int out_size, void* d_ws, size_t ws_size,
                              hipStream_t stream) {
  hipFuncSetAttribute(reinterpret_cast<const void*>(graphblock_kernel),
                      hipFuncAttributeMaxDynamicSharedMemorySize, SMEM_BYTES);
  dim3 grid(B_ * J_);
  dim3 block(512);
  graphblock_kernel<<<grid, block, SMEM_BYTES, stream>>>(
      (const float*)d_in[0],  // x
      (const float*)d_in[1],  // attention_feat
      (const float*)d_in[2],  // ln_w
      (const float*)d_in[3],  // ln_b
      (const float*)d_in[4],  // Uw
      (const float*)d_in[5],  // Ub
      (const float*)d_in[6],  // Vw
      (const float*)d_in[7],  // Vb
      (const float*)d_in[8],  // bn_w
      (const float*)d_in[9],  // bn_b
      (const float*)d_in[10], // ls1
      (float*)d_out);
}

// Round 4
// 311.010 us; speedup vs baseline: 6.9554x; 1.5287x over previous
//
#include <hip/hip_runtime.h>

#define B_ 64
#define T_ 243
#define J_ 17
#define C_ 128
#define JC (J_*C_)            // 2176
#define NTOT (B_*T_*J_*C_)    // 33841152

// LDS layout (bytes):
//   [0,      65536)  ylds : bf16 [256][128], swizzled: byte = r*256 + (col_byte ^ ((r&7)<<4))
//   [65536, 133120)  yv   : bf16 rows, stride 264 B, 256 rows
//   [133120,135168)  nbr  : u64 [256]  (4 x u16 idx)
//   [135168,136192)  bnw_s: f32 [256] (pre-scaled)
//   [136192,137216)  bnb_s: f32 [256]
#define YOFF    0
#define YVOFF   65536
#define NBROFF  133120
#define BNWOFF  135168
#define BNBOFF  136192
#define SMEM_BYTES 137216

typedef short bf16x8 __attribute__((ext_vector_type(8)));
typedef float f32x4 __attribute__((ext_vector_type(4)));

__device__ __forceinline__ float b2f(unsigned short v){ return __uint_as_float(((unsigned)v) << 16); }
__device__ __forceinline__ unsigned short f2bf(float f){
  unsigned u = __float_as_uint(f);
  u += 0x7fffu + ((u >> 16) & 1u);   // RNE
  return (unsigned short)(u >> 16);
}
__device__ __forceinline__ bf16x8 pack8(float4 a, float4 b){
  union { bf16x8 v; unsigned short u[8]; } r;
  r.u[0]=f2bf(a.x); r.u[1]=f2bf(a.y); r.u[2]=f2bf(a.z); r.u[3]=f2bf(a.w);
  r.u[4]=f2bf(b.x); r.u[5]=f2bf(b.y); r.u[6]=f2bf(b.z); r.u[7]=f2bf(b.w);
  return r.v;
}

// 7-op insert of idx-packed float x into descending (a0>=a1>=a2>=a3)
#define PINS(x, a0,a1,a2,a3) do { \
  float t_ = fmaxf(a0,(x)), m_ = fminf(a0,(x)); a0 = t_; \
  float t2_ = fmaxf(a1,m_); m_ = fminf(a1,m_); a1 = t2_; \
  float t3_ = fmaxf(a2,m_); m_ = fminf(a2,m_); a2 = t3_; \
  a3 = fmaxf(a3,m_); \
} while(0)

extern "C" __global__ void __launch_bounds__(1024)
graphblock_kernel(const float* __restrict__ x, const float* __restrict__ att,
                  const float* __restrict__ lnw, const float* __restrict__ lnb,
                  const float* __restrict__ Uw, const float* __restrict__ Ubv,
                  const float* __restrict__ Vw, const float* __restrict__ Vbv,
                  const float* __restrict__ bnw, const float* __restrict__ bnb,
                  const float* __restrict__ ls1, float* __restrict__ out)
{
  extern __shared__ char smem[];
  const int tid = threadIdx.x;
  const int w   = tid >> 6;     // wave 0..15
  const int l   = tid & 63;
  const int lr  = l & 15;
  const int lg  = l >> 4;
  const int n = blockIdx.x;
  const int b = n / J_, j = n % J_;
  const long nbase = (long)b*T_*JC + (long)j*C_;

  // stage BN tables
  if (tid < T_) {
    ((float*)(smem+BNWOFF))[tid] = bnw[tid] * rsqrtf(1.0f + 1e-5f);
    ((float*)(smem+BNBOFF))[tid] = bnb[tid];
  }

  // ---------- Phase A: LayerNorm -> ylds (bf16, swizzled); rows 243..255 zero ----------
  {
    const float lw0 = lnw[2*l], lw1 = lnw[2*l+1];
    const float lb0 = lnb[2*l], lb1 = lnb[2*l+1];
    for (int r = w; r < 256; r += 16) {
      unsigned pk = 0u;
      if (r < T_) {
        const float2* xr = (const float2*)(x + nbase + (long)r*JC);
        float2 p = xr[l];
        float s = p.x + p.y;
        float q = p.x*p.x + p.y*p.y;
        #pragma unroll
        for (int m=1;m<64;m<<=1){ s += __shfl_xor(s,m,64); q += __shfl_xor(q,m,64); }
        float mu = s * (1.0f/128.0f);
        float var = q * (1.0f/128.0f) - mu*mu;
        float rs = rsqrtf(var + 1e-5f);
        pk = (unsigned)f2bf((p.x-mu)*rs*lw0 + lb0)
           | ((unsigned)f2bf((p.y-mu)*rs*lw1 + lb1) << 16);
      }
      *(unsigned*)(smem + YOFF + r*256 + ((4*l) ^ ((r&7)<<4))) = pk;
    }
  }

  // prefetch U/V weight fragments for this wave's column slice (used after sim)
  const int rh = w >> 3;            // row half for UV pass
  const int cs = w & 7;             // col slice
  const int cr = cs*16 + lr;        // output channel
  bf16x8 vfr[4], ufr[4];
  #pragma unroll
  for (int kk=0;kk<4;kk++){
    const float4* pv = (const float4*)(Vw + cr*C_ + kk*32 + lg*8);
    vfr[kk] = pack8(pv[0], pv[1]);
    const float4* pu = (const float4*)(Uw + cr*C_ + kk*32 + lg*8);
    ufr[kk] = pack8(pu[0], pu[1]);
  }
  const float vb  = Vbv[cr];
  const float ubc = Ubv[cr];
  const float lsc = ls1[cr];

  __syncthreads();   // barrier 1: ylds + BN tables ready

  // ---------- Phase C: sim (MFMA) + in-register top-4 ----------
  {
    const int ar = w*16 + lr;                 // wave owns rows w*16..w*16+15
    bf16x8 afr[4];
    #pragma unroll
    for (int kk=0;kk<4;kk++)
      afr[kk] = *(const bf16x8*)(smem + YOFF + ar*256 + ((kk*64 + lg*16) ^ ((ar&7)<<4)));

    float v0[4], v1[4], v2[4], v3[4];
    #pragma unroll
    for (int r=0;r<4;r++){ v0[r]=-3e38f; v1[r]=-3e38f; v2[r]=-3e38f; v3[r]=-3e38f; }

    for (int st=0; st<16; st++){
      const int br = st*16 + lr;
      f32x4 acc = {0.f,0.f,0.f,0.f};
      #pragma unroll
      for (int kk=0;kk<4;kk++){
        bf16x8 bfr = *(const bf16x8*)(smem + YOFF + br*256 + ((kk*64 + lg*16) ^ ((br&7)<<4)));
        acc = __builtin_amdgcn_mfma_f32_16x16x32_bf16(afr[kk], bfr, acc, 0,0,0);
      }
      const int sidx = st*16 + lr;            // col this lane holds
      const bool ok = (sidx < T_);
      #pragma unroll
      for (int reg=0;reg<4;reg++){
        unsigned u = (__float_as_uint(acc[reg]) & 0xffffff00u) | (unsigned)(sidx & 0xff);
        float pv = ok ? __uint_as_float(u) : -3e38f;
        PINS(pv, v0[reg], v1[reg], v2[reg], v3[reg]);
      }
    }
    // merge across the 16 lr lanes (same lg)
    #pragma unroll
    for (int m=1;m<16;m<<=1){
      #pragma unroll
      for (int reg=0;reg<4;reg++){
        float w0=__shfl_xor(v0[reg],m,64), w1=__shfl_xor(v1[reg],m,64);
        float w2=__shfl_xor(v2[reg],m,64), w3=__shfl_xor(v3[reg],m,64);
        PINS(w0, v0[reg],v1[reg],v2[reg],v3[reg]);
        PINS(w1, v0[reg],v1[reg],v2[reg],v3[reg]);
        PINS(w2, v0[reg],v1[reg],v2[reg],v3[reg]);
        PINS(w3, v0[reg],v1[reg],v2[reg],v3[reg]);
      }
    }
    if (lr == 0){
      #pragma unroll
      for (int reg=0;reg<4;reg++){
        int row = w*16 + lg*4 + reg;
        unsigned long long pk =
            (unsigned long long)(__float_as_uint(v0[reg]) & 0xffu)
          | ((unsigned long long)(__float_as_uint(v1[reg]) & 0xffu) << 16)
          | ((unsigned long long)(__float_as_uint(v2[reg]) & 0xffu) << 32)
          | ((unsigned long long)(__float_as_uint(v3[reg]) & 0xffu) << 48);
        *(unsigned long long*)(smem + NBROFF + row*8) = pk;
      }
    }
  }

  // ---------- Pass 1: fused yV (-> LDS) + yU (-> regs) MFMA ----------
  float hu[8][4];
  {
    #pragma unroll
    for (int tt=0; tt<8; tt++){
      const int arow = (rh*8+tt)*16 + lr;
      bf16x8 a[4];
      #pragma unroll
      for (int kk=0;kk<4;kk++)
        a[kk] = *(const bf16x8*)(smem + YOFF + arow*256 + ((kk*64+lg*16) ^ ((arow&7)<<4)));
      f32x4 aV = {0.f,0.f,0.f,0.f}, aU = {0.f,0.f,0.f,0.f};
      #pragma unroll
      for (int kk=0;kk<4;kk++){
        aV = __builtin_amdgcn_mfma_f32_16x16x32_bf16(a[kk], vfr[kk], aV, 0,0,0);
        aU = __builtin_amdgcn_mfma_f32_16x16x32_bf16(a[kk], ufr[kk], aU, 0,0,0);
      }
      #pragma unroll
      for (int reg=0;reg<4;reg++){
        hu[tt][reg] = aU[reg];
        const int t = (rh*8+tt)*16 + lg*4 + reg;
        *(unsigned short*)(smem + YVOFF + t*264 + 2*cr) = f2bf(aV[reg] + vb);
      }
    }
  }
  __syncthreads();   // barrier 2: nbr + yv ready

  // ---------- Pass 2: gather-agg + BN + ReLU + epilogue ----------
  {
    #pragma unroll
    for (int tt=0; tt<8; tt++){
      #pragma unroll
      for (int reg=0;reg<4;reg++){
        const int t = (rh*8+tt)*16 + lg*4 + reg;
        if (t < T_){
          unsigned long long nb = *(const unsigned long long*)(smem + NBROFF + t*8);
          const int s0i = (int)(nb & 0xffu), s1i = (int)((nb>>16)&0xffu),
                    s2i = (int)((nb>>32)&0xffu), s3i = (int)((nb>>48)&0xffu);
          float agg = b2f(*(const unsigned short*)(smem + YVOFF + s0i*264 + 2*cr))
                    + b2f(*(const unsigned short*)(smem + YVOFF + s1i*264 + 2*cr))
                    + b2f(*(const unsigned short*)(smem + YVOFF + s2i*264 + 2*cr))
                    + b2f(*(const unsigned short*)(smem + YVOFF + s3i*264 + 2*cr));
          float h = 0.25f*agg + hu[tt][reg] + ubc;
          h = h * ((const float*)(smem+BNWOFF))[t] + ((const float*)(smem+BNBOFF))[t];
          float yo = b2f(*(const unsigned short*)(smem + YOFF + t*256 + ((2*cr) ^ ((t&7)<<4))));
          float z = fmaxf(0.f, yo + h);
          float gx = lsc * z;
          long g = nbase + (long)t*JC + cr;
          out[g] = gx + x[g] + att[g];
          out[NTOT + g] = gx * 0.5f;
        }
      }
    }
  }
}

extern "C" void kernel_launch(void* const* d_in, const int* in_sizes, int n_in,
                              void* d_out, int out_size, void* d_ws, size_t ws_size,
                              hipStream_t stream) {
  hipFuncSetAttribute(reinterpret_cast<const void*>(graphblock_kernel),
                      hipFuncAttributeMaxDynamicSharedMemorySize, SMEM_BYTES);
  dim3 grid(B_ * J_);
  dim3 block(1024);
  graphblock_kernel<<<grid, block, SMEM_BYTES, stream>>>(
      (const float*)d_in[0],  // x
      (const float*)d_in[1],  // attention_feat
      (const float*)d_in[2],  // ln_w
      (const float*)d_in[3],  // ln_b
      (const float*)d_in[4],  // Uw
      (const float*)d_in[5],  // Ub
      (const float*)d_in[6],  // Vw
      (const float*)d_in[7],  // Vb
      (const float*)d_in[8],  // bn_w
      (const float*)d_in[9],  // bn_b
      (const float*)d_in[10], // ls1
      (float*)d_out);
}

// Round 6
// 293.646 us; speedup vs baseline: 7.3667x; 1.0591x over previous
//
#include <hip/hip_runtime.h>

#define B_ 64
#define T_ 243
#define J_ 17
#define C_ 128
#define JC (J_*C_)            // 2176
#define NTOT (B_*T_*J_*C_)    // 33841152

// LDS layout (bytes):
//   [0,      65536)  ylds : bf16 [256][128], swizzled: byte = r*256 + (col_byte ^ ((r&7)<<4))
//   [65536, 133120)  yv   : bf16 rows, stride 264 B, 256 rows
//   [133120,135168)  nbr  : u64 [256]  (4 x u16 idx)
//   [135168,136192)  bnw_s: f32 [256] (pre-scaled)
//   [136192,137216)  bnb_s: f32 [256]
#define YOFF    0
#define YVOFF   65536
#define NBROFF  133120
#define BNWOFF  135168
#define BNBOFF  136192
#define SMEM_BYTES 137216

typedef short bf16x8 __attribute__((ext_vector_type(8)));
typedef float f32x4 __attribute__((ext_vector_type(4)));

__device__ __forceinline__ unsigned short f2bf(float f){
  unsigned u = __float_as_uint(f);
  u += 0x7fffu + ((u >> 16) & 1u);   // RNE
  return (unsigned short)(u >> 16);
}
__device__ __forceinline__ unsigned pk2(float a, float b){
  return (unsigned)f2bf(a) | ((unsigned)f2bf(b) << 16);
}
__device__ __forceinline__ bf16x8 pack8(float4 a, float4 b){
  union { bf16x8 v; unsigned u[4]; } r;
  r.u[0]=pk2(a.x,a.y); r.u[1]=pk2(a.z,a.w); r.u[2]=pk2(b.x,b.y); r.u[3]=pk2(b.z,b.w);
  return r.v;
}

#define UNPK(q,f0,f1,f2,f3) do{ unsigned lo_=(unsigned)(q), hi_=(unsigned)((q)>>32); \
  f0=__uint_as_float(lo_<<16); f1=__uint_as_float(lo_&0xffff0000u); \
  f2=__uint_as_float(hi_<<16); f3=__uint_as_float(hi_&0xffff0000u);}while(0)

// 7-op insert of x into descending (a0>=a1>=a2>=a3)
#define PINS(x, a0,a1,a2,a3) do { \
  float t_ = fmaxf(a0,(x)), m_ = fminf(a0,(x)); a0 = t_; \
  float t2_ = fmaxf(a1,m_); m_ = fminf(a1,m_); a1 = t2_; \
  float t3_ = fmaxf(a2,m_); m_ = fminf(a2,m_); a2 = t3_; \
  a3 = fmaxf(a3,m_); \
} while(0)
#define MM(p,q) do { float h_=fmaxf(p,q); q=fminf(p,q); p=h_; } while(0)

extern "C" __global__ void __launch_bounds__(1024,4)
graphblock_kernel(const float* __restrict__ x, const float* __restrict__ att,
                  const float* __restrict__ lnw, const float* __restrict__ lnb,
                  const float* __restrict__ Uw, const float* __restrict__ Ubv,
                  const float* __restrict__ Vw, const float* __restrict__ Vbv,
                  const float* __restrict__ bnw, const float* __restrict__ bnb,
                  const float* __restrict__ ls1, float* __restrict__ out)
{
  extern __shared__ char smem[];
  const int tid = threadIdx.x;
  const int w = tid >> 6, l = tid & 63;
  const int lr = l & 15, lg = l >> 4;
  const int n = blockIdx.x, b = n / J_, j = n % J_;
  const long nbase = (long)b*T_*JC + (long)j*C_;

  const int cs = w & 7, rh = w >> 3;   // UV-pass roles: channel slice / t-half
  const int ch0 = cs*16 + lg*4;        // lane's 4-channel base (pass1/2)
  const int crw = cs*16 + lr;          // weight row this lane loads (frag layout)

  // ---- early weight loads (consumed after barrier 1; hidden under LN) ----
  float4 vraw[8], uraw[8];
  #pragma unroll
  for (int kk=0;kk<4;kk++){
    const float4* pv = (const float4*)(Vw + crw*C_ + kk*32 + lg*8);
    vraw[2*kk] = pv[0]; vraw[2*kk+1] = pv[1];
    const float4* pu = (const float4*)(Uw + crw*C_ + kk*32 + lg*8);
    uraw[2*kk] = pu[0]; uraw[2*kk+1] = pu[1];
  }
  const float4 vb4 = *(const float4*)(Vbv + ch0);
  const float4 ub4 = *(const float4*)(Ubv + ch0);
  const float4 ls4 = *(const float4*)(ls1 + ch0);

  if (tid < 256) {
    bool v = tid < T_;
    ((float*)(smem+BNWOFF))[tid] = v ? bnw[tid]*rsqrtf(1.0f+1e-5f) : 0.f;
    ((float*)(smem+BNBOFF))[tid] = v ? bnb[tid] : 0.f;
  }

  // ---- Phase A: LayerNorm (float4 loads, 2 rows per wave-iter) ----
  {
    const int lh = l >> 5, lc = l & 31;
    const float4 lw4 = *(const float4*)(lnw + lc*4);
    const float4 lb4 = *(const float4*)(lnb + lc*4);
    #pragma unroll
    for (int i=0;i<8;i++){
      int r = i*32 + w*2 + lh;
      unsigned p0=0u, p1=0u;
      if (r < T_) {
        float4 p = *(const float4*)(x + nbase + (long)r*JC + lc*4);
        float s = (p.x+p.y)+(p.z+p.w);
        float q = (p.x*p.x+p.y*p.y)+(p.z*p.z+p.w*p.w);
        #pragma unroll
        for (int m=1;m<32;m<<=1){ s += __shfl_xor(s,m,64); q += __shfl_xor(q,m,64); }
        float mu = s*(1.f/128.f);
        float rs = rsqrtf(q*(1.f/128.f)-mu*mu+1e-5f);
        p0 = pk2((p.x-mu)*rs*lw4.x+lb4.x, (p.y-mu)*rs*lw4.y+lb4.y);
        p1 = pk2((p.z-mu)*rs*lw4.z+lb4.z, (p.w-mu)*rs*lw4.w+lb4.w);
      }
      char* dst = smem + YOFF + r*256 + ((8*lc) ^ ((r&7)<<4));
      ((unsigned*)dst)[0]=p0; ((unsigned*)dst)[1]=p1;
    }
  }

  // pack weight fragments (A-operand rows = channels)
  bf16x8 vfr[4], ufr[4];
  #pragma unroll
  for (int kk=0;kk<4;kk++){
    vfr[kk]=pack8(vraw[2*kk],vraw[2*kk+1]);
    ufr[kk]=pack8(uraw[2*kk],uraw[2*kk+1]);
  }

  __syncthreads();   // barrier 1: ylds + BN ready

  // ---- Phase C: sim (MFMA) + in-register top-4, merge-network butterfly ----
  {
    const int ar = w*16 + lr;
    bf16x8 afr[4];
    #pragma unroll
    for (int kk=0;kk<4;kk++)
      afr[kk] = *(const bf16x8*)(smem + YOFF + ar*256 + ((kk*64+lg*16) ^ ((ar&7)<<4)));
    float v0[4],v1[4],v2[4],v3[4];
    #pragma unroll
    for (int r=0;r<4;r++){ v0[r]=-3e38f; v1[r]=-3e38f; v2[r]=-3e38f; v3[r]=-3e38f; }
    #pragma unroll 4
    for (int st=0; st<16; st++){
      const int br = st*16 + lr;
      f32x4 acc = {0.f,0.f,0.f,0.f};
      #pragma unroll
      for (int kk=0;kk<4;kk++){
        bf16x8 bfr = *(const bf16x8*)(smem + YOFF + br*256 + ((kk*64+lg*16) ^ ((br&7)<<4)));
        acc = __builtin_amdgcn_mfma_f32_16x16x32_bf16(afr[kk], bfr, acc, 0,0,0);
      }
      const int sidx = st*16 + lr;          // <= 255, fits 8 bits
      const bool okc = sidx < T_;
      #pragma unroll
      for (int reg=0;reg<4;reg++){
        unsigned u = (__float_as_uint(acc[reg]) & 0xffffff00u) | (unsigned)sidx;
        float pv = okc ? __uint_as_float(u) : -3e38f;
        PINS(pv, v0[reg],v1[reg],v2[reg],v3[reg]);
      }
    }
    // butterfly merge across 16 lr lanes: sorted-merge network (4 max + sort4)
    #pragma unroll
    for (int m=1;m<16;m<<=1){
      #pragma unroll
      for (int reg=0;reg<4;reg++){
        float c0=__shfl_xor(v0[reg],m,64), c1=__shfl_xor(v1[reg],m,64),
              c2=__shfl_xor(v2[reg],m,64), c3=__shfl_xor(v3[reg],m,64);
        float d0=fmaxf(v0[reg],c3), d1=fmaxf(v1[reg],c2),
              d2=fmaxf(v2[reg],c1), d3=fmaxf(v3[reg],c0);
        MM(d0,d1); MM(d2,d3); MM(d0,d2); MM(d1,d3); MM(d1,d2);
        v0[reg]=d0; v1[reg]=d1; v2[reg]=d2; v3[reg]=d3;
      }
    }
    if (lr==0){
      #pragma unroll
      for (int reg=0;reg<4;reg++){
        int row = w*16 + lg*4 + reg;
        unsigned long long pk =
            (unsigned long long)(__float_as_uint(v0[reg]) & 0xffu)
          | ((unsigned long long)(__float_as_uint(v1[reg]) & 0xffu) << 16)
          | ((unsigned long long)(__float_as_uint(v2[reg]) & 0xffu) << 32)
          | ((unsigned long long)(__float_as_uint(v3[reg]) & 0xffu) << 48);
        *(unsigned long long*)(smem + NBROFF + row*8) = pk;
      }
    }
  }

  // ---- Pass 1: fused yV/yU MFMA, CHANNEL-MAJOR (D: row=ch, col=t) ----
  float hu[8][4];
  #pragma unroll
  for (int tt=0; tt<8; tt++){
    const int tile = rh*8+tt;
    const int arow = tile*16 + lr;
    bf16x8 a[4];
    #pragma unroll
    for (int kk=0;kk<4;kk++)
      a[kk] = *(const bf16x8*)(smem + YOFF + arow*256 + ((kk*64+lg*16) ^ ((arow&7)<<4)));
    f32x4 aV={0.f,0.f,0.f,0.f}, aU={0.f,0.f,0.f,0.f};
    #pragma unroll
    for (int kk=0;kk<4;kk++){
      aV = __builtin_amdgcn_mfma_f32_16x16x32_bf16(vfr[kk], a[kk], aV, 0,0,0);
      aU = __builtin_amdgcn_mfma_f32_16x16x32_bf16(ufr[kk], a[kk], aU, 0,0,0);
    }
    const int t = tile*16 + lr;
    char* dst = smem + YVOFF + t*264 + 2*ch0;
    ((unsigned*)dst)[0] = pk2(aV[0]+vb4.x, aV[1]+vb4.y);
    ((unsigned*)dst)[1] = pk2(aV[2]+vb4.z, aV[3]+vb4.w);
    hu[tt][0]=aU[0]; hu[tt][1]=aU[1]; hu[tt][2]=aU[2]; hu[tt][3]=aU[3];
  }

  __syncthreads();   // barrier 2: nbr + yv ready

  // ---- Pass 2: gather + BN + ReLU + epilogue (float4 VMEM) ----
  #pragma unroll
  for (int tt=0; tt<8; tt++){
    const int t = (rh*8+tt)*16 + lr;
    const bool ok = t < T_;
    const long g = nbase + (long)t*JC + ch0;
    float4 x4 = {0,0,0,0}, a4 = {0,0,0,0};
    if (ok){ x4 = *(const float4*)(x+g); a4 = *(const float4*)(att+g); }
    unsigned long long nb = *(const unsigned long long*)(smem + NBROFF + t*8);
    const int s0 = (int)(nb & 0xffu), s1 = (int)((nb>>16)&0xffu),
              s2 = (int)((nb>>32)&0xffu), s3 = (int)((nb>>48)&0xffu);
    float ag0,ag1,ag2,ag3, f0,f1,f2,f3;
    unsigned long long q;
    q = *(const unsigned long long*)(smem+YVOFF + s0*264 + 2*ch0); UNPK(q,ag0,ag1,ag2,ag3);
    q = *(const unsigned long long*)(smem+YVOFF + s1*264 + 2*ch0); UNPK(q,f0,f1,f2,f3);
    ag0+=f0; ag1+=f1; ag2+=f2; ag3+=f3;
    q = *(const unsigned long long*)(smem+YVOFF + s2*264 + 2*ch0); UNPK(q,f0,f1,f2,f3);
    ag0+=f0; ag1+=f1; ag2+=f2; ag3+=f3;
    q = *(const unsigned long long*)(smem+YVOFF + s3*264 + 2*ch0); UNPK(q,f0,f1,f2,f3);
    ag0+=f0; ag1+=f1; ag2+=f2; ag3+=f3;
    unsigned long long yq = *(const unsigned long long*)(smem + YOFF + t*256 + ((2*ch0) ^ ((t&7)<<4)));
    float yo0,yo1,yo2,yo3; UNPK(yq,yo0,yo1,yo2,yo3);
    const float bw = ((const float*)(smem+BNWOFF))[t];
    const float bb = ((const float*)(smem+BNBOFF))[t];
    f32x4 o, gf;
    {
      float h = (0.25f*ag0 + hu[tt][0] + ub4.x)*bw + bb;
      float gx = ls4.x * fmaxf(0.f, yo0 + h);
      o[0] = gx + a4.x + x4.x; gf[0] = gx*0.5f;
    }{
      float h = (0.25f*ag1 + hu[tt][1] + ub4.y)*bw + bb;
      float gx = ls4.y * fmaxf(0.f, yo1 + h);
      o[1] = gx + a4.y + x4.y; gf[1] = gx*0.5f;
    }{
      float h = (0.25f*ag2 + hu[tt][2] + ub4.z)*bw + bb;
      float gx = ls4.z * fmaxf(0.f, yo2 + h);
      o[2] = gx + a4.z + x4.z; gf[2] = gx*0.5f;
    }{
      float h = (0.25f*ag3 + hu[tt][3] + ub4.w)*bw + bb;
      float gx = ls4.w * fmaxf(0.f, yo3 + h);
      o[3] = gx + a4.w + x4.w; gf[3] = gx*0.5f;
    }
    if (ok){
      __builtin_nontemporal_store(o,  (f32x4*)(out+g));
      __builtin_nontemporal_store(gf, (f32x4*)(out+NTOT+g));
    }
  }
}

extern "C" void kernel_launch(void* const* d_in, const int* in_sizes, int n_in,
                              void* d_out, int out_size, void* d_ws, size_t ws_size,
                              hipStream_t stream) {
  hipFuncSetAttribute(reinterpret_cast<const void*>(graphblock_kernel),
                      hipFuncAttributeMaxDynamicSharedMemorySize, SMEM_BYTES);
  dim3 grid(B_ * J_);
  dim3 block(1024);
  graphblock_kernel<<<grid, block, SMEM_BYTES, stream>>>(
      (const float*)d_in[0],  // x
      (const float*)d_in[1],  // attention_feat
      (const float*)d_in[2],  // ln_w
      (const float*)d_in[3],  // ln_b
      (const float*)d_in[4],  // Uw
      (const float*)d_in[5],  // Ub
      (const float*)d_in[6],  // Vw
      (const float*)d_in[7],  // Vb
      (const float*)d_in[8],  // bn_w
      (const float*)d_in[9],  // bn_b
      (const float*)d_in[10], // ls1
      (float*)d_out);
}